// Round 5
// baseline (582.365 us; speedup 1.0000x reference)
//
#include <hip/hip_runtime.h>
#include <math.h>

typedef __attribute__((ext_vector_type(8))) short short8;
typedef __attribute__((ext_vector_type(4))) float float4v;
typedef __attribute__((ext_vector_type(16))) float float16v;
typedef __attribute__((ext_vector_type(4))) unsigned short ushort4v;
typedef unsigned short u16;
typedef unsigned int u32;

#define NB 64
#define NN 2048
#define FD 128
#define UD 64
#define KT 384

__device__ __forceinline__ u16 f2bf(float f) {
    unsigned int u = __float_as_uint(f);
    u += 0x7fffu + ((u >> 16) & 1u);
    return (u16)(u >> 16);
}
__device__ __forceinline__ float bf2f(u16 s) {
    return __uint_as_float(((unsigned int)s) << 16);
}
__device__ __forceinline__ float sigmoidf_(float x) {
    return 1.0f / (1.0f + expf(-x));
}
// async global->LDS, 16B per lane; LDS dest must be wave-uniform base + lane*16
__device__ __forceinline__ void gl2lds16(const u16* g, u16* l) {
    __builtin_amdgcn_global_load_lds((const __attribute__((address_space(1))) unsigned int*)g,
                                     (__attribute__((address_space(3))) unsigned int*)l,
                                     16, 0, 0);
}

// ---------------------------------------------------------------- rownorm
__global__ void k_rownorm(const float* __restrict__ adj, float* __restrict__ d_inv) {
    int m = blockIdx.x;
    const float4v* row = (const float4v*)(adj + (size_t)m * NN);
    float s = 0.f;
    for (int i = threadIdx.x; i < NN / 4; i += 256) {
        float4v v = row[i];
        s += v.x + v.y + v.z + v.w;
    }
    __shared__ float red[4];
    for (int off = 32; off; off >>= 1) s += __shfl_down(s, off, 64);
    if ((threadIdx.x & 63) == 0) red[threadIdx.x >> 6] = s;
    __syncthreads();
    if (threadIdx.x == 0) {
        float t = red[0] + red[1] + red[2] + red[3] + 1.0f;
        d_inv[m] = 1.0f / t;
    }
}

// ---------------------------------------------------------------- adjT (bf16, transposed + normalized)
__global__ void k_adjT(const float* __restrict__ adj, const float* __restrict__ d_inv,
                       u16* __restrict__ adjT) {
    __shared__ u16 T[64 * 72];
    int m0 = blockIdx.x * 64;
    int n0 = blockIdx.y * 64;
    int t = threadIdx.x;
    for (int p = 0; p < 4; ++p) {
        int idx = t + 256 * p;
        int i  = idx >> 4;
        int n4 = idx & 15;
        int m = m0 + i;
        float4v v = *(const float4v*)(adj + (size_t)m * NN + n0 + n4 * 4);
        float di = d_inv[m];
        float vv[4] = {v.x, v.y, v.z, v.w};
#pragma unroll
        for (int j = 0; j < 4; ++j) {
            int n = n0 + n4 * 4 + j;
            float a = vv[j] + ((m == n) ? 1.0f : 0.0f);
            T[(n4 * 4 + j) * 72 + i] = f2bf(a * di);
        }
    }
    __syncthreads();
    for (int p = 0; p < 2; ++p) {
        int idx = t + 256 * p;
        int n  = idx >> 3;
        int m8 = (idx & 7) * 8;
        *(short8*)(adjT + (size_t)(n0 + n) * NN + m0 + m8) = *(const short8*)(T + n * 72 + m8);
    }
}

// ---------------------------------------------------------------- W reorder: Wt[o][kd*128+f] = W[f*3+kd][o]
__global__ void k_reorderW(const float* __restrict__ W, u16* __restrict__ Wt, int OD) {
    int idx = blockIdx.x * 256 + threadIdx.x;
    if (idx >= KT * OD) return;
    int o  = idx % OD;
    int kp = idx / OD;
    int kd = kp >> 7, f = kp & 127;
    Wt[(size_t)o * KT + kp] = f2bf(W[(size_t)(f * 3 + kd) * OD + o]);
}

// ---------------------------------------------------------------- xcat: X0c[(b*128+f)][m] = concat(x,h)
__global__ void k_xcat(const float* __restrict__ x, const float* __restrict__ h,
                       u16* __restrict__ X0c) {
    __shared__ u16 T[128 * 136];
    int m0 = blockIdx.x * 128;
    int b  = blockIdx.y;
    int t = threadIdx.x;
    const float* srcs[2] = { x + (size_t)b * (NN * 64), h + (size_t)b * (NN * 64) };
    for (int s = 0; s < 2; ++s) {
        const float* src = srcs[s];
        for (int p = 0; p < 8; ++p) {
            int idx = t + 256 * p;
            int mi = idx >> 4;
            int f4 = idx & 15;
            float4v v = *(const float4v*)(src + (size_t)(m0 + mi) * 64 + f4 * 4);
            float vv[4] = {v.x, v.y, v.z, v.w};
#pragma unroll
            for (int j = 0; j < 4; ++j)
                T[(s * 64 + f4 * 4 + j) * 136 + mi] = f2bf(vv[j]);
        }
    }
    __syncthreads();
    for (int p = 0; p < 8; ++p) {
        int idx = t + 256 * p;
        int f  = idx >> 4;
        int m8 = (idx & 15) * 8;
        *(short8*)(X0c + ((size_t)(b * FD + f)) * NN + m0 + m8) = *(const short8*)(T + f * 136 + m8);
    }
}

// ---------------------------------------------------------------- GEMM, (64*MT)x128 tile, 32x32x16 MFMA
// Fragment-ordered LDS: element (row=g*32+ln, kchunk=2ks+hi) at slot ((g*2+ks)*64 + hi*32 + ln)*16B
// => every ds_read_b128 is base + lane*16 (conflict-free), staged directly by global_load_lds.
// A: adjT [2048][2048] (N-operand). Bc: [NC][2048] (M-operand). Cc[c][n] = sum_m Bc[c][m]*A[n][m]
// mode 0: Cc = A@Bc ; mode 1: Cc = 2*A@Bc - Sub.  grid: (cBlocks, 16), cBlocks = NC/(64*MT)
template<int MT>
__global__ __launch_bounds__(256, 2)
void k_gemm(const u16* __restrict__ A, const u16* __restrict__ Bc,
            u16* __restrict__ Cc, const u16* __restrict__ Sub, int mode, int cBlocks) {
    __shared__ u16 SM[8192 + 4096 * MT];     // A dbuf 2x4096 + B dbuf 2x2048*MT (u16)
    u16* A0 = SM;            u16* A1 = SM + 4096;
    u16* B0 = SM + 8192;     u16* B1 = SM + 8192 + 2048 * MT;

    int id = blockIdx.x + cBlocks * blockIdx.y;
    int band = cBlocks >> 3;
    int g = id & 7, s = id >> 3;
    int cb = g * band + (s % band);
    int nb = s / band;
    int c0 = cb * (64 * MT);
    int n0 = nb * 128;

    int t = threadIdx.x;
    int wave = t >> 6, lane = t & 63;
    int wy = wave & 1, wx = wave >> 1;
    int ln = lane & 31, hi = lane >> 5;
    int l16 = lane * 8;                      // u16 offset of this lane's 16B slot

    // staging source coords (loop-invariant): slot T -> (row, kchunk)
    const u16* gaP[2];
#pragma unroll
    for (int i = 0; i < 2; ++i) {
        int T = t + 256 * i;
        int row = (T >> 7) * 32 + (T & 31);
        int ko  = (((T >> 6) & 1) * 2 + ((T >> 5) & 1)) * 8;
        gaP[i] = A + (size_t)(n0 + row) * 2048 + ko;
    }
    const u16* gbP[MT];
#pragma unroll
    for (int i = 0; i < MT; ++i) {
        int T = t + 256 * i;
        int row = (T >> 7) * 32 + (T & 31);
        int ko  = (((T >> 6) & 1) * 2 + ((T >> 5) & 1)) * 8;
        gbP[i] = Bc + (size_t)(c0 + row) * 2048 + ko;
    }

    float16v acc[MT][2];
#pragma unroll
    for (int i = 0; i < MT; ++i)
#pragma unroll
        for (int j = 0; j < 2; ++j)
#pragma unroll
            for (int e = 0; e < 16; ++e) acc[i][j][e] = 0.f;

    // prologue prefetch -> stage 0
#pragma unroll
    for (int i = 0; i < 2; ++i)  gl2lds16(gaP[i], A0 + (t + 256 * i) * 8);
#pragma unroll
    for (int i = 0; i < MT; ++i) gl2lds16(gbP[i], B0 + (t + 256 * i) * 8);

#pragma unroll 2
    for (int it = 0; it < 64; ++it) {
        u16* Ac = (it & 1) ? A1 : A0;
        u16* Bs = (it & 1) ? B1 : B0;
        __syncthreads();                     // stage(it) ready; stage(it^1) reads done
        if (it + 1 < 64) {
            int ko = (it + 1) * 32;
            u16* An = (it & 1) ? A0 : A1;
            u16* Bn = (it & 1) ? B0 : B1;
#pragma unroll
            for (int i = 0; i < 2; ++i)  gl2lds16(gaP[i] + ko, An + (t + 256 * i) * 8);
#pragma unroll
            for (int i = 0; i < MT; ++i) gl2lds16(gbP[i] + ko, Bn + (t + 256 * i) * 8);
        }
        short8 fa[2][MT], fb[2][2];
#pragma unroll
        for (int ks = 0; ks < 2; ++ks) {
#pragma unroll
            for (int mt = 0; mt < MT; ++mt)
                fa[ks][mt] = *(const short8*)(Bs + ((wx * MT + mt) * 2 + ks) * 512 + l16);
#pragma unroll
            for (int nt = 0; nt < 2; ++nt)
                fb[ks][nt] = *(const short8*)(Ac + ((wy * 2 + nt) * 2 + ks) * 512 + l16);
        }
#pragma unroll
        for (int ks = 0; ks < 2; ++ks)
#pragma unroll
            for (int mt = 0; mt < MT; ++mt)
#pragma unroll
                for (int nt = 0; nt < 2; ++nt)
                    acc[mt][nt] = __builtin_amdgcn_mfma_f32_32x32x16_bf16(fa[ks][mt], fb[ks][nt], acc[mt][nt], 0, 0, 0);
    }

    // ---- epilogue: per wx-half through LDS transpose (MT*32 x 136), coalesced 64B-line stores
    __syncthreads();                         // K-loop LDS reads done; SM reusable
#pragma unroll
    for (int p = 0; p < 2; ++p) {
        if (p) __syncthreads();              // pass0 copy-out done before pass1 writes
        if (wx == p) {
#pragma unroll
            for (int mt = 0; mt < MT; ++mt)
#pragma unroll
                for (int nt = 0; nt < 2; ++nt)
#pragma unroll
                    for (int e = 0; e < 16; ++e) {
                        int cl = mt * 32 + 4 * hi + 8 * (e >> 2) + (e & 3);
                        int nl = wy * 64 + nt * 32 + ln;
                        SM[cl * 136 + nl] = f2bf(acc[mt][nt][e]);
                    }
        }
        __syncthreads();
#pragma unroll
        for (int pp = 0; pp < MT / 2; ++pp) {
            int idx = t + 256 * pp;          // MT*32 rows x 4 chunks
            int cl = idx >> 2;
            int nc = (idx & 3) * 8;          // 16B chunk within 64B line
            u16* drow = Cc + (size_t)(c0 + p * (MT * 32) + cl) * 2048 + n0 + nc;
            const u16* subr = Sub + (size_t)(c0 + p * (MT * 32) + cl) * 2048 + n0 + nc;
            const u16* srow = SM + cl * 136 + nc;
#pragma unroll
            for (int u = 0; u < 4; ++u) {    // 4 chunks, 64B stride -> full row of 128 n
                short8 v = *(const short8*)(srow + u * 32);
                if (mode == 1) {
                    short8 sv = *(const short8*)(subr + u * 32);
                    short8 o;
#pragma unroll
                    for (int e = 0; e < 8; ++e)
                        o[e] = (short)f2bf(2.f * bf2f((u16)v[e]) - bf2f((u16)sv[e]));
                    *(short8*)(drow + u * 32) = o;
                } else {
                    *(short8*)(drow + u * 32) = v;
                }
            }
        }
    }
}

// ---------------------------------------------------------------- ru projection (K=384) + sigmoid + r*h / u
__global__ __launch_bounds__(256)
void k_ruW(const u16* __restrict__ X0c, const u16* __restrict__ X1c, const u16* __restrict__ X2c,
           const u16* __restrict__ Wt, const float* __restrict__ bias,
           const float* __restrict__ hx,
           u16* __restrict__ RH0c, float* __restrict__ Utc) {
    __shared__ u16 As[128 * 40];   // padded (scatter-transposed, not global_load_lds)
    __shared__ u16 Bs[128 * 32];   // unpadded (global_load_lds)
    int rt = blockIdx.x;           // 0..1023
    int b  = rt >> 4;
    int m0 = (rt & 15) * 128;
    int t = threadIdx.x;
    int wave = t >> 6, lane = t & 63;
    int wr = (wave >> 1) * 64, wc = (wave & 1) * 64;
    int lr = lane & 15, q = lane >> 4;
    const u16* Xs[3] = {X0c, X1c, X2c};
    int f2 = t & 15;
    int m8 = (t >> 4) * 8;
    const u16* gw = Wt + (size_t)(t >> 2) * KT + (t & 3) * 8;
    u16* lw0 = Bs + t * 8;  u16* lw1 = Bs + (t + 256) * 8;
    const u16* gw1 = Wt + (size_t)((t >> 2) + 64) * KT + (t & 3) * 8;

    float4v acc[4][4];
#pragma unroll
    for (int i = 0; i < 4; ++i)
#pragma unroll
        for (int j = 0; j < 4; ++j) { acc[i][j].x = 0.f; acc[i][j].y = 0.f; acc[i][j].z = 0.f; acc[i][j].w = 0.f; }

    for (int it = 0; it < 12; ++it) {
        int k0 = it * 32;
        int kd = k0 >> 7, fb = k0 & 127;
        const u16* src = Xs[kd] + ((size_t)(b * FD + fb)) * NN + m0;
        gl2lds16(gw  + k0, lw0);
        gl2lds16(gw1 + k0, lw1);
        short8 v0 = *(const short8*)(src + (size_t)(2 * f2)     * NN + m8);
        short8 v1 = *(const short8*)(src + (size_t)(2 * f2 + 1) * NN + m8);
#pragma unroll
        for (int e = 0; e < 8; ++e)
            *(u32*)(As + (m8 + e) * 40 + 2 * f2) = (u32)(u16)v0[e] | ((u32)(u16)v1[e] << 16);
        __syncthreads();
        short8 af[4], bfr[4];
#pragma unroll
        for (int i = 0; i < 4; ++i) af[i]  = *(const short8*)(As + (wr + 16 * i + lr) * 40 + q * 8);
#pragma unroll
        for (int j = 0; j < 4; ++j) bfr[j] = *(const short8*)(Bs + (wc + 16 * j + lr) * 32 + q * 8);
#pragma unroll
        for (int i = 0; i < 4; ++i)
#pragma unroll
            for (int j = 0; j < 4; ++j)
                acc[i][j] = __builtin_amdgcn_mfma_f32_16x16x32_bf16(af[i], bfr[j], acc[i][j], 0, 0, 0);
        __syncthreads();
    }
#pragma unroll
    for (int i = 0; i < 4; ++i) {
        int m = m0 + wr + 16 * i + q * 4;
#pragma unroll
        for (int j = 0; j < 4; ++j) {
            int o = wc + 16 * j + lr;
            float bia = bias[o];
            float4v v = acc[i][j];
            if (o < 64) {
                ushort4v pk;
#pragma unroll
                for (int r = 0; r < 4; ++r) {
                    float sg = sigmoidf_(v[r] + bia);
                    float hh = hx[(size_t)b * (NN * 64) + (size_t)(m + r) * 64 + o];
                    pk[r] = f2bf(sg * hh);
                }
                *(ushort4v*)(RH0c + ((size_t)(b * UD + o)) * NN + m) = pk;
            } else {
                int gg = o - 64;
                float4v u;
#pragma unroll
                for (int r = 0; r < 4; ++r) u[r] = sigmoidf_(v[r] + bia);
                *(float4v*)(Utc + ((size_t)(b * UD + gg)) * NN + m) = u;
            }
        }
    }
}

// ---------------------------------------------------------------- c projection (K=384) + tanh + final combine
__global__ __launch_bounds__(256)
void k_cW(const u16* __restrict__ X0c, const u16* __restrict__ X1c, const u16* __restrict__ X2c,
          const u16* __restrict__ RH0c, const u16* __restrict__ RH1c, const u16* __restrict__ RH2c,
          const u16* __restrict__ Wt, const float* __restrict__ bias,
          const float* __restrict__ hx, const float* __restrict__ Utc,
          float* __restrict__ out) {
    __shared__ u16 As[256 * 40];
    __shared__ u16 Bs[64 * 32];
    int rt = blockIdx.x;           // 0..511
    int b  = rt >> 3;
    int m0 = (rt & 7) * 256;
    int t = threadIdx.x;
    int wave = t >> 6, lane = t & 63;
    int lr = lane & 15, q = lane >> 4;
    const u16* Xs[3] = {X0c, X1c, X2c};
    const u16* Rs[3] = {RH0c, RH1c, RH2c};
    const u16* gw = Wt + (size_t)(t >> 2) * KT + (t & 3) * 8;
    u16* lw = Bs + t * 8;

    float4v acc[4][4];
#pragma unroll
    for (int i = 0; i < 4; ++i)
#pragma unroll
        for (int j = 0; j < 4; ++j) { acc[i][j].x = 0.f; acc[i][j].y = 0.f; acc[i][j].z = 0.f; acc[i][j].w = 0.f; }

    for (int it = 0; it < 12; ++it) {
        int k0 = it * 32;
        int kd = k0 >> 7, fb = k0 & 127;
        const u16* src;
        if (fb < 64) src = Xs[kd] + ((size_t)(b * FD + fb)) * NN + m0;
        else         src = Rs[kd] + ((size_t)(b * UD + (fb - 64))) * NN + m0;
        gl2lds16(gw + k0, lw);
#pragma unroll
        for (int p = 0; p < 2; ++p) {
            int idx = t + 256 * p;
            int f2 = idx & 15;
            int m8 = (idx >> 4) * 8;
            short8 v0 = *(const short8*)(src + (size_t)(2 * f2)     * NN + m8);
            short8 v1 = *(const short8*)(src + (size_t)(2 * f2 + 1) * NN + m8);
#pragma unroll
            for (int e = 0; e < 8; ++e)
                *(u32*)(As + (m8 + e) * 40 + 2 * f2) = (u32)(u16)v0[e] | ((u32)(u16)v1[e] << 16);
        }
        __syncthreads();
        short8 af[4], bfr[4];
#pragma unroll
        for (int i = 0; i < 4; ++i) af[i]  = *(const short8*)(As + (64 * wave + 16 * i + lr) * 40 + q * 8);
#pragma unroll
        for (int j = 0; j < 4; ++j) bfr[j] = *(const short8*)(Bs + (16 * j + lr) * 32 + q * 8);
#pragma unroll
        for (int i = 0; i < 4; ++i)
#pragma unroll
            for (int j = 0; j < 4; ++j)
                acc[i][j] = __builtin_amdgcn_mfma_f32_16x16x32_bf16(af[i], bfr[j], acc[i][j], 0, 0, 0);
        __syncthreads();
    }
#pragma unroll
    for (int i = 0; i < 4; ++i) {
        int m = m0 + 64 * wave + 16 * i + q * 4;
#pragma unroll
        for (int j = 0; j < 4; ++j) {
            int o = 16 * j + lr;
            float bia = bias[o];
            float4v v = acc[i][j];
            float4v u = *(const float4v*)(Utc + ((size_t)(b * UD + o)) * NN + m);
#pragma unroll
            for (int r = 0; r < 4; ++r) {
                float c = tanhf(v[r] + bia);
                size_t idx = (size_t)b * (NN * 64) + (size_t)(m + r) * 64 + o;
                float hh = hx[idx];
                out[idx] = u[r] * hh + (1.0f - u[r]) * c;
            }
        }
    }
}

// ---------------------------------------------------------------- launch
extern "C" void kernel_launch(void* const* d_in, const int* in_sizes, int n_in,
                              void* d_out, int out_size, void* d_ws, size_t ws_size,
                              hipStream_t stream) {
    const float* x    = (const float*)d_in[0];
    const float* hx   = (const float*)d_in[1];
    const float* adj  = (const float*)d_in[2];
    const float* W_ru = (const float*)d_in[3];
    const float* b_ru = (const float*)d_in[4];
    const float* W_c  = (const float*)d_in[5];
    const float* b_c  = (const float*)d_in[6];
    float* out = (float*)d_out;

    char* ws = (char*)d_ws;
    size_t off = 0;
    auto alloc = [&](size_t bytes) -> void* {
        void* p = ws + off;
        off += (bytes + 255) & ~(size_t)255;
        return p;
    };
    float* d_inv = (float*)alloc((size_t)NN * 4);
    u16* adjT  = (u16*)alloc((size_t)NN * NN * 2);
    u16* Wt_ru = (u16*)alloc((size_t)FD * KT * 2);
    u16* Wt_c  = (u16*)alloc((size_t)UD * KT * 2);
    u16* X0c = (u16*)alloc((size_t)NB * FD * NN * 2);
    u16* X1c = (u16*)alloc((size_t)NB * FD * NN * 2);
    u16* X2c = (u16*)alloc((size_t)NB * FD * NN * 2);
    u16* RH0c = (u16*)alloc((size_t)NB * UD * NN * 2);
    u16* RH1c = (u16*)alloc((size_t)NB * UD * NN * 2);
    u16* RH2c = (u16*)alloc((size_t)NB * UD * NN * 2);
    float* Utc = (float*)alloc((size_t)NB * UD * NN * 4);

    k_rownorm<<<dim3(NN), dim3(256), 0, stream>>>(adj, d_inv);
    k_adjT<<<dim3(32, 32), dim3(256), 0, stream>>>(adj, d_inv, adjT);
    k_reorderW<<<dim3((KT * FD + 255) / 256), dim3(256), 0, stream>>>(W_ru, Wt_ru, FD);
    k_reorderW<<<dim3((KT * UD + 255) / 256), dim3(256), 0, stream>>>(W_c, Wt_c, UD);
    k_xcat<<<dim3(16, NB), dim3(256), 0, stream>>>(x, hx, X0c);
    // X1 = A @ X0 ; X2 = 2 A @ X1 - X0   (8192 columns, 32 c-blocks of 256)
    k_gemm<4><<<dim3(32, 16), dim3(256), 0, stream>>>(adjT, X0c, X1c, X0c, 0, 32);
    k_gemm<4><<<dim3(32, 16), dim3(256), 0, stream>>>(adjT, X1c, X2c, X0c, 1, 32);
    k_ruW<<<dim3(1024), dim3(256), 0, stream>>>(X0c, X1c, X2c, Wt_ru, b_ru, hx, RH0c, Utc);
    // RH1 = A @ RH0 ; RH2 = 2 A @ RH1 - RH0   (4096 columns, 32 c-blocks of 128)
    k_gemm<2><<<dim3(32, 16), dim3(256), 0, stream>>>(adjT, RH0c, RH1c, RH0c, 0, 32);
    k_gemm<2><<<dim3(32, 16), dim3(256), 0, stream>>>(adjT, RH1c, RH2c, RH0c, 1, 32);
    k_cW<<<dim3(512), dim3(256), 0, stream>>>(X0c, X1c, X2c, RH0c, RH1c, RH2c, Wt_c, b_c, hx, Utc, out);
}

// Round 6
// 471.970 us; speedup vs baseline: 1.2339x; 1.2339x over previous
//
#include <hip/hip_runtime.h>
#include <math.h>

typedef __attribute__((ext_vector_type(8))) short short8;
typedef __attribute__((ext_vector_type(4))) float float4v;
typedef __attribute__((ext_vector_type(16))) float float16v;
typedef __attribute__((ext_vector_type(4))) unsigned short ushort4v;
typedef unsigned short u16;
typedef unsigned int u32;

#define NB 64
#define NN 2048
#define FD 128
#define UD 64
#define KT 384

// ---- PANEL FORMAT for all k-major GEMM operands (k-dim = 2048) ----
// matrix[row][k]  ->  flat[(rg*64 + kg)*1024 + (c*32 + r)*8 + j]
//   rg=row>>5, r=row&31, kg=k>>5, c=(k>>3)&3, j=k&7
// A 32x32 panel = 2KB contiguous, slot (c*32+r) of 16B == MFMA fragment order.

__device__ __forceinline__ u16 f2bf(float f) {
    unsigned int u = __float_as_uint(f);
    u += 0x7fffu + ((u >> 16) & 1u);
    return (u16)(u >> 16);
}
__device__ __forceinline__ float bf2f(u16 s) {
    return __uint_as_float(((unsigned int)s) << 16);
}
__device__ __forceinline__ float sigmoidf_(float x) {
    return 1.0f / (1.0f + expf(-x));
}
// async global->LDS, 16B per lane; LDS dest = wave-uniform base + lane*16
__device__ __forceinline__ void gl2lds16(const u16* g, u16* l) {
    __builtin_amdgcn_global_load_lds((const __attribute__((address_space(1))) unsigned int*)g,
                                     (__attribute__((address_space(3))) unsigned int*)l,
                                     16, 0, 0);
}

// ---------------------------------------------------------------- rownorm
__global__ void k_rownorm(const float* __restrict__ adj, float* __restrict__ d_inv) {
    int m = blockIdx.x;
    const float4v* row = (const float4v*)(adj + (size_t)m * NN);
    float s = 0.f;
    for (int i = threadIdx.x; i < NN / 4; i += 256) {
        float4v v = row[i];
        s += v.x + v.y + v.z + v.w;
    }
    __shared__ float red[4];
    for (int off = 32; off; off >>= 1) s += __shfl_down(s, off, 64);
    if ((threadIdx.x & 63) == 0) red[threadIdx.x >> 6] = s;
    __syncthreads();
    if (threadIdx.x == 0) {
        float t = red[0] + red[1] + red[2] + red[3] + 1.0f;
        d_inv[m] = 1.0f / t;
    }
}

// ---------------------------------------------------------------- adjT panels: adjT[n][m]=(adj[m][n]+I)*dinv[m]
__global__ void k_adjT(const float* __restrict__ adj, const float* __restrict__ d_inv,
                       u16* __restrict__ adjT) {
    __shared__ u16 T[64 * 72];
    int m0 = blockIdx.x * 64;
    int n0 = blockIdx.y * 64;
    int t = threadIdx.x;
    for (int p = 0; p < 4; ++p) {
        int idx = t + 256 * p;
        int i  = idx >> 4;
        int n4 = idx & 15;
        int m = m0 + i;
        float4v v = *(const float4v*)(adj + (size_t)m * NN + n0 + n4 * 4);
        float di = d_inv[m];
        float vv[4] = {v.x, v.y, v.z, v.w};
#pragma unroll
        for (int j = 0; j < 4; ++j) {
            int n = n0 + n4 * 4 + j;
            float a = vv[j] + ((m == n) ? 1.0f : 0.0f);
            T[(n4 * 4 + j) * 72 + i] = f2bf(a * di);
        }
    }
    __syncthreads();
    // write 4 panels (2 rg x 2 kg), 512 slots
#pragma unroll
    for (int p = 0; p < 2; ++p) {
        int S = t + 256 * p;
        int rgl = S >> 8, kgl = (S >> 7) & 1, s = S & 127;
        int c = s >> 5, r = s & 31;
        short8 v = *(const short8*)(T + (rgl * 32 + r) * 72 + kgl * 32 + c * 8);
        *(short8*)(adjT + ((size_t)((n0 >> 5) + rgl) * 64 + (m0 >> 5) + kgl) * 1024 + s * 8) = v;
    }
}

// ---------------------------------------------------------------- W reorder: Wt[o][kd*128+f] (row-major)
__global__ void k_reorderW(const float* __restrict__ W, u16* __restrict__ Wt, int OD) {
    int idx = blockIdx.x * 256 + threadIdx.x;
    if (idx >= KT * OD) return;
    int o  = idx % OD;
    int kp = idx / OD;
    int kd = kp >> 7, f = kp & 127;
    Wt[(size_t)o * KT + kp] = f2bf(W[(size_t)(f * 3 + kd) * OD + o]);
}

// ---------------------------------------------------------------- xcat -> X0c panels (rows b*128+f, k=m)
__global__ void k_xcat(const float* __restrict__ x, const float* __restrict__ h,
                       u16* __restrict__ X0c) {
    __shared__ u16 T[128 * 136];
    int m0 = blockIdx.x * 128;
    int b  = blockIdx.y;
    int t = threadIdx.x;
    const float* srcs[2] = { x + (size_t)b * (NN * 64), h + (size_t)b * (NN * 64) };
    for (int s = 0; s < 2; ++s) {
        const float* src = srcs[s];
        for (int p = 0; p < 8; ++p) {
            int idx = t + 256 * p;
            int mi = idx >> 4;
            int f4 = idx & 15;
            float4v v = *(const float4v*)(src + (size_t)(m0 + mi) * 64 + f4 * 4);
            float vv[4] = {v.x, v.y, v.z, v.w};
#pragma unroll
            for (int j = 0; j < 4; ++j)
                T[(s * 64 + f4 * 4 + j) * 136 + mi] = f2bf(vv[j]);
        }
    }
    __syncthreads();
    // 16 panels (4 fg x 4 kg), 2048 slots
#pragma unroll
    for (int p = 0; p < 8; ++p) {
        int S = t + 256 * p;
        int fgl = S >> 9, kgl = (S >> 7) & 3, s = S & 127;
        int c = s >> 5, r = s & 31;
        short8 v = *(const short8*)(T + (fgl * 32 + r) * 136 + kgl * 32 + c * 8);
        *(short8*)(X0c + ((size_t)(b * 4 + fgl) * 64 + (m0 >> 5) + kgl) * 1024 + s * 8) = v;
    }
}

// ---------------------------------------------------------------- GEMM, (64*MT)x128 tile, 32x32x16 MFMA
// All operands panel-format. A: adjT (N-operand, 2048 rows). Bc (M-operand, NC rows).
// Cc[c][n] = sum_m Bc[c][m]*A[n][m]; mode 1: 2*acc - Sub. Output panel-format.
// Staging: wave reads 1KB contiguous; LDS = fragment order; zero conflicts.
template<int MT>
__global__ __launch_bounds__(256, 2)
void k_gemm(const u16* __restrict__ A, const u16* __restrict__ Bc,
            u16* __restrict__ Cc, const u16* __restrict__ Sub, int mode, int cBlocks) {
    __shared__ u16 SM[8192 + 4096 * MT];     // A dbuf 2x4096 + B dbuf 2x2048*MT (u16)
    u16* A0 = SM;            u16* A1 = SM + 4096;
    u16* B0 = SM + 8192;     u16* B1 = SM + 8192 + 2048 * MT;

    int id = blockIdx.x + cBlocks * blockIdx.y;
    int band = cBlocks >> 3;
    int g = id & 7, s = id >> 3;
    int cb = g * band + (s % band);
    int nb = s / band;
    int c0 = cb * (64 * MT);
    int n0 = nb * 128;

    int t = threadIdx.x;
    int wave = t >> 6, lane = t & 63;
    int wy = wave & 1, wx = wave >> 1;
    int ln = lane & 31, hi = lane >> 5;
    int l16 = lane * 8;

    // staging sources: slot T covers panel p=T>>7, slot s=T&127; contiguous per wave
    const u16* gaP[2];
#pragma unroll
    for (int i = 0; i < 2; ++i) {
        int T = t + 256 * i;
        gaP[i] = A + ((size_t)((n0 >> 5) + (T >> 7)) * 64) * 1024 + (size_t)(T & 127) * 8;
    }
    const u16* gbP[MT];
#pragma unroll
    for (int i = 0; i < MT; ++i) {
        int T = t + 256 * i;
        gbP[i] = Bc + ((size_t)((c0 >> 5) + (T >> 7)) * 64) * 1024 + (size_t)(T & 127) * 8;
    }

    float16v acc[MT][2];
#pragma unroll
    for (int i = 0; i < MT; ++i)
#pragma unroll
        for (int j = 0; j < 2; ++j)
#pragma unroll
            for (int e = 0; e < 16; ++e) acc[i][j][e] = 0.f;

    // prologue prefetch -> stage 0 (kg=0)
#pragma unroll
    for (int i = 0; i < 2; ++i)  gl2lds16(gaP[i], A0 + (t + 256 * i) * 8);
#pragma unroll
    for (int i = 0; i < MT; ++i) gl2lds16(gbP[i], B0 + (t + 256 * i) * 8);

#pragma unroll 2
    for (int it = 0; it < 64; ++it) {
        u16* Ac = (it & 1) ? A1 : A0;
        u16* Bs = (it & 1) ? B1 : B0;
        __syncthreads();                     // stage(it) ready; stage(it^1) reads done
        if (it + 1 < 64) {
            int ko = (it + 1) * 1024;        // next kg panel offset (u16)
            u16* An = (it & 1) ? A0 : A1;
            u16* Bn = (it & 1) ? B0 : B1;
#pragma unroll
            for (int i = 0; i < 2; ++i)  gl2lds16(gaP[i] + ko, An + (t + 256 * i) * 8);
#pragma unroll
            for (int i = 0; i < MT; ++i) gl2lds16(gbP[i] + ko, Bn + (t + 256 * i) * 8);
        }
        short8 fa[2][MT], fb[2][2];
#pragma unroll
        for (int ks = 0; ks < 2; ++ks) {
#pragma unroll
            for (int mt = 0; mt < MT; ++mt)
                fa[ks][mt] = *(const short8*)(Bs + ((wx * MT + mt) * 2 + ks) * 512 + l16);
#pragma unroll
            for (int nt = 0; nt < 2; ++nt)
                fb[ks][nt] = *(const short8*)(Ac + ((wy * 2 + nt) * 2 + ks) * 512 + l16);
        }
#pragma unroll
        for (int ks = 0; ks < 2; ++ks)
#pragma unroll
            for (int mt = 0; mt < MT; ++mt)
#pragma unroll
                for (int nt = 0; nt < 2; ++nt)
                    acc[mt][nt] = __builtin_amdgcn_mfma_f32_32x32x16_bf16(fa[ks][mt], fb[ks][nt], acc[mt][nt], 0, 0, 0);
    }

    // ---- epilogue: per wx-half via LDS transpose, then panel-format coalesced stores
    __syncthreads();
#pragma unroll
    for (int p = 0; p < 2; ++p) {
        if (p) __syncthreads();
        if (wx == p) {
#pragma unroll
            for (int mt = 0; mt < MT; ++mt)
#pragma unroll
                for (int nt = 0; nt < 2; ++nt)
#pragma unroll
                    for (int e = 0; e < 16; ++e) {
                        int cl = mt * 32 + 4 * hi + 8 * (e >> 2) + (e & 3);
                        int nl = wy * 64 + nt * 32 + ln;
                        SM[cl * 136 + nl] = f2bf(acc[mt][nt][e]);
                    }
        }
        __syncthreads();
        // MT*512 slots: rgl = S>>9, kgl = (S>>7)&3, s = S&127
#pragma unroll
        for (int pp = 0; pp < 2 * MT; ++pp) {
            int S = t + 256 * pp;
            int rgl = S >> 9, kgl = (S >> 7) & 3, sl = S & 127;
            int c = sl >> 5, r = sl & 31;
            short8 v = *(const short8*)(SM + (rgl * 32 + r) * 136 + kgl * 32 + c * 8);
            size_t gaddr = ((size_t)((c0 >> 5) + p * MT + rgl) * 64 + (n0 >> 5) + kgl) * 1024 + sl * 8;
            if (mode == 1) {
                short8 sv = *(const short8*)(Sub + gaddr);
                short8 o;
#pragma unroll
                for (int e = 0; e < 8; ++e)
                    o[e] = (short)f2bf(2.f * bf2f((u16)v[e]) - bf2f((u16)sv[e]));
                *(short8*)(Cc + gaddr) = o;
            } else {
                *(short8*)(Cc + gaddr) = v;
            }
        }
    }
}

// ---------------------------------------------------------------- ru projection (K=384) + sigmoid + r*h / u
// X* panel-format. W fragment-ordered staging. RH0c written panel-format; Utc row-major fp32.
__global__ __launch_bounds__(256)
void k_ruW(const u16* __restrict__ X0c, const u16* __restrict__ X1c, const u16* __restrict__ X2c,
           const u16* __restrict__ Wt, const float* __restrict__ bias,
           const float* __restrict__ hx,
           u16* __restrict__ RH0c, float* __restrict__ Utc) {
    __shared__ u16 As[128 * 40];   // m-rows x f (padded scatter-transpose)
    __shared__ u16 Bs[4096];       // W fragment-ordered (512 slots)
    int rt = blockIdx.x;           // 0..1023
    int b  = rt >> 4;
    int m0 = (rt & 15) * 128;
    int t = threadIdx.x;
    int wave = t >> 6, lane = t & 63;
    int wr = (wave >> 1) * 64, wc = (wave & 1) * 64;
    int lr = lane & 15, q = lane >> 4;
    const u16* Xs[3] = {X0c, X1c, X2c};
    int f2 = t & 15;
    int m8 = (t >> 4) * 8;
    // W staging: slot T -> o=(T>>6)*16+(T&15), kq=(T>>4)&3
    const u16* gw[2];
#pragma unroll
    for (int i = 0; i < 2; ++i) {
        int T = t + 256 * i;
        gw[i] = Wt + (size_t)((T >> 6) * 16 + (T & 15)) * KT + ((T >> 4) & 3) * 8;
    }

    float4v acc[4][4];
#pragma unroll
    for (int i = 0; i < 4; ++i)
#pragma unroll
        for (int j = 0; j < 4; ++j) { acc[i][j].x = 0.f; acc[i][j].y = 0.f; acc[i][j].z = 0.f; acc[i][j].w = 0.f; }

    for (int it = 0; it < 12; ++it) {
        int k0 = it * 32;
        int kd = k0 >> 7, fb = k0 & 127;
        gl2lds16(gw[0] + k0, Bs + t * 8);
        gl2lds16(gw[1] + k0, Bs + (t + 256) * 8);
        // panel read: features 2f2,2f2+1 (adjacent slots), m-chunk m8
        const u16* base = Xs[kd] + ((size_t)(b * 4 + (fb >> 5)) * 64 + (m0 >> 5) + (m8 >> 5)) * 1024
                          + (((m8 >> 3) & 3) * 32 + 2 * f2) * 8;
        short8 v0 = *(const short8*)(base);
        short8 v1 = *(const short8*)(base + 8);
#pragma unroll
        for (int e = 0; e < 8; ++e)
            *(u32*)(As + (m8 + e) * 40 + 2 * f2) = (u32)(u16)v0[e] | ((u32)(u16)v1[e] << 16);
        __syncthreads();
        short8 af[4], bfr[4];
#pragma unroll
        for (int i = 0; i < 4; ++i) af[i]  = *(const short8*)(As + (wr + 16 * i + lr) * 40 + q * 8);
#pragma unroll
        for (int j = 0; j < 4; ++j) bfr[j] = *(const short8*)(Bs + ((wc >> 4) + j) * 512 + lane * 8);
#pragma unroll
        for (int i = 0; i < 4; ++i)
#pragma unroll
            for (int j = 0; j < 4; ++j)
                acc[i][j] = __builtin_amdgcn_mfma_f32_16x16x32_bf16(af[i], bfr[j], acc[i][j], 0, 0, 0);
        __syncthreads();
    }
#pragma unroll
    for (int i = 0; i < 4; ++i) {
        int m = m0 + wr + 16 * i + q * 4;
#pragma unroll
        for (int j = 0; j < 4; ++j) {
            int o = wc + 16 * j + lr;
            float bia = bias[o];
            float4v v = acc[i][j];
            if (o < 64) {
                ushort4v pk;
#pragma unroll
                for (int r = 0; r < 4; ++r) {
                    float sg = sigmoidf_(v[r] + bia);
                    float hh = hx[(size_t)b * (NN * 64) + (size_t)(m + r) * 64 + o];
                    pk[r] = f2bf(sg * hh);
                }
                // panel write: row = b*64+o, k = m..m+3
                size_t ga = ((size_t)(b * 2 + (o >> 5)) * 64 + (m >> 5)) * 1024
                            + (((m >> 3) & 3) * 32 + (o & 31)) * 8 + (m & 7);
                *(ushort4v*)(RH0c + ga) = pk;
            } else {
                int gg = o - 64;
                float4v u;
#pragma unroll
                for (int r = 0; r < 4; ++r) u[r] = sigmoidf_(v[r] + bia);
                *(float4v*)(Utc + ((size_t)(b * UD + gg)) * NN + m) = u;
            }
        }
    }
}

// ---------------------------------------------------------------- c projection (K=384) + tanh + final combine
__global__ __launch_bounds__(256)
void k_cW(const u16* __restrict__ X0c, const u16* __restrict__ X1c, const u16* __restrict__ X2c,
          const u16* __restrict__ RH0c, const u16* __restrict__ RH1c, const u16* __restrict__ RH2c,
          const u16* __restrict__ Wt, const float* __restrict__ bias,
          const float* __restrict__ hx, const float* __restrict__ Utc,
          float* __restrict__ out) {
    __shared__ u16 As[256 * 40];
    __shared__ u16 Bs[2048];       // W fragment-ordered (256 slots)
    int rt = blockIdx.x;           // 0..511
    int b  = rt >> 3;
    int m0 = (rt & 7) * 256;
    int t = threadIdx.x;
    int wave = t >> 6, lane = t & 63;
    int lr = lane & 15, q = lane >> 4;
    const u16* Xs[3] = {X0c, X1c, X2c};
    const u16* Rs[3] = {RH0c, RH1c, RH2c};
    const u16* gw = Wt + (size_t)((t >> 6) * 16 + (t & 15)) * KT + ((t >> 4) & 3) * 8;

    float4v acc[4][4];
#pragma unroll
    for (int i = 0; i < 4; ++i)
#pragma unroll
        for (int j = 0; j < 4; ++j) { acc[i][j].x = 0.f; acc[i][j].y = 0.f; acc[i][j].z = 0.f; acc[i][j].w = 0.f; }

    for (int it = 0; it < 12; ++it) {
        int k0 = it * 32;
        int kd = k0 >> 7, fb = k0 & 127;
        const u16* mat; int rg;
        if (fb < 64) { mat = Xs[kd]; rg = b * 4 + (fb >> 5); }
        else         { mat = Rs[kd]; rg = b * 2 + ((fb - 64) >> 5); }
        gl2lds16(gw + k0, Bs + t * 8);
#pragma unroll
        for (int p = 0; p < 2; ++p) {
            int idx = t + 256 * p;
            int f2 = idx & 15;
            int m8 = (idx >> 4) * 8;        // 0..248
            const u16* base = mat + ((size_t)rg * 64 + (m0 >> 5) + (m8 >> 5)) * 1024
                              + (((m8 >> 3) & 3) * 32 + 2 * f2) * 8;
            short8 v0 = *(const short8*)(base);
            short8 v1 = *(const short8*)(base + 8);
#pragma unroll
            for (int e = 0; e < 8; ++e)
                *(u32*)(As + (m8 + e) * 40 + 2 * f2) = (u32)(u16)v0[e] | ((u32)(u16)v1[e] << 16);
        }
        __syncthreads();
        short8 af[4], bfr[4];
#pragma unroll
        for (int i = 0; i < 4; ++i) af[i]  = *(const short8*)(As + (64 * wave + 16 * i + lr) * 40 + q * 8);
#pragma unroll
        for (int j = 0; j < 4; ++j) bfr[j] = *(const short8*)(Bs + j * 512 + lane * 8);
#pragma unroll
        for (int i = 0; i < 4; ++i)
#pragma unroll
            for (int j = 0; j < 4; ++j)
                acc[i][j] = __builtin_amdgcn_mfma_f32_16x16x32_bf16(af[i], bfr[j], acc[i][j], 0, 0, 0);
        __syncthreads();
    }
#pragma unroll
    for (int i = 0; i < 4; ++i) {
        int m = m0 + 64 * wave + 16 * i + q * 4;
#pragma unroll
        for (int j = 0; j < 4; ++j) {
            int o = 16 * j + lr;
            float bia = bias[o];
            float4v v = acc[i][j];
            float4v u = *(const float4v*)(Utc + ((size_t)(b * UD + o)) * NN + m);
#pragma unroll
            for (int r = 0; r < 4; ++r) {
                float c = tanhf(v[r] + bia);
                size_t idx = (size_t)b * (NN * 64) + (size_t)(m + r) * 64 + o;
                float hh = hx[idx];
                out[idx] = u[r] * hh + (1.0f - u[r]) * c;
            }
        }
    }
}

// ---------------------------------------------------------------- launch
extern "C" void kernel_launch(void* const* d_in, const int* in_sizes, int n_in,
                              void* d_out, int out_size, void* d_ws, size_t ws_size,
                              hipStream_t stream) {
    const float* x    = (const float*)d_in[0];
    const float* hx   = (const float*)d_in[1];
    const float* adj  = (const float*)d_in[2];
    const float* W_ru = (const float*)d_in[3];
    const float* b_ru = (const float*)d_in[4];
    const float* W_c  = (const float*)d_in[5];
    const float* b_c  = (const float*)d_in[6];
    float* out = (float*)d_out;

    char* ws = (char*)d_ws;
    size_t off = 0;
    auto alloc = [&](size_t bytes) -> void* {
        void* p = ws + off;
        off += (bytes + 255) & ~(size_t)255;
        return p;
    };
    float* d_inv = (float*)alloc((size_t)NN * 4);
    u16* adjT  = (u16*)alloc((size_t)NN * NN * 2);
    u16* Wt_ru = (u16*)alloc((size_t)FD * KT * 2);
    u16* Wt_c  = (u16*)alloc((size_t)UD * KT * 2);
    u16* X0c = (u16*)alloc((size_t)NB * FD * NN * 2);
    u16* X1c = (u16*)alloc((size_t)NB * FD * NN * 2);
    u16* X2c = (u16*)alloc((size_t)NB * FD * NN * 2);
    u16* RH0c = (u16*)alloc((size_t)NB * UD * NN * 2);
    u16* RH1c = (u16*)alloc((size_t)NB * UD * NN * 2);
    u16* RH2c = (u16*)alloc((size_t)NB * UD * NN * 2);
    float* Utc = (float*)alloc((size_t)NB * UD * NN * 4);

    k_rownorm<<<dim3(NN), dim3(256), 0, stream>>>(adj, d_inv);
    k_adjT<<<dim3(32, 32), dim3(256), 0, stream>>>(adj, d_inv, adjT);
    k_reorderW<<<dim3((KT * FD + 255) / 256), dim3(256), 0, stream>>>(W_ru, Wt_ru, FD);
    k_reorderW<<<dim3((KT * UD + 255) / 256), dim3(256), 0, stream>>>(W_c, Wt_c, UD);
    k_xcat<<<dim3(16, NB), dim3(256), 0, stream>>>(x, hx, X0c);
    // X1 = A @ X0 ; X2 = 2 A @ X1 - X0   (8192 rows, 32 c-blocks of 256)
    k_gemm<4><<<dim3(32, 16), dim3(256), 0, stream>>>(adjT, X0c, X1c, X0c, 0, 32);
    k_gemm<4><<<dim3(32, 16), dim3(256), 0, stream>>>(adjT, X1c, X2c, X0c, 1, 32);
    k_ruW<<<dim3(1024), dim3(256), 0, stream>>>(X0c, X1c, X2c, Wt_ru, b_ru, hx, RH0c, Utc);
    // RH1 = A @ RH0 ; RH2 = 2 A @ RH1 - RH0   (4096 rows, 32 c-blocks of 128)
    k_gemm<2><<<dim3(32, 16), dim3(256), 0, stream>>>(adjT, RH0c, RH1c, RH0c, 0, 32);
    k_gemm<2><<<dim3(32, 16), dim3(256), 0, stream>>>(adjT, RH1c, RH2c, RH0c, 1, 32);
    k_cW<<<dim3(512), dim3(256), 0, stream>>>(X0c, X1c, X2c, RH0c, RH1c, RH2c, Wt_c, b_c, hx, Utc, out);
}